// Round 4
// baseline (91.646 us; speedup 1.0000x reference)
//
#include <hip/hip_runtime.h>

#define BB 64
#define TT 8192
#define CC 64

typedef float vfloat4 __attribute__((ext_vector_type(4)));

// DPP cross-lane helpers (VALU-only, no LDS). CTRL: 0x141 = row_half_mirror
// (lane^7 within each 8-group), 0x4E = quad_perm [2,3,0,1] (lane^2),
// 0xB1 = quad_perm [1,0,3,2] (lane^1). All stay within an 8-lane group.
template<int CTRL>
__device__ __forceinline__ float dppf(float x) {
    return __int_as_float(__builtin_amdgcn_update_dpp(
        0, __float_as_int(x), CTRL, 0xF, 0xF, true));
}
template<int CTRL>
__device__ __forceinline__ int dppi(int x) {
    return __builtin_amdgcn_update_dpp(0, x, CTRL, 0xF, 0xF, true);
}

// ---------------- K1: masked argmax over C=64 -> preds[B*T] ----------------
// 8 lanes per frame, 8 cols/lane (2x float4), DPP-only reduction.
// Tie-break: first (lowest) index, exact vs np.argmax.
__global__ __launch_bounds__(256) void k_argmax(const float* __restrict__ logits,
                                                const int* __restrict__ mask,
                                                int* __restrict__ preds) {
    const int lane = threadIdx.x & 63;
    const int wave = threadIdx.x >> 6;
    const int sub  = lane & 7;    // column octet within frame
    const int fidx = lane >> 3;   // frame within group of 8
    const int wavesPerBlock = blockDim.x >> 6;
    const int gw = blockIdx.x * wavesPerBlock + wave;
    const int nw = gridDim.x * wavesPerBlock;
    const int ngroups = (BB * TT) >> 3;   // 8 frames per wave-iteration

    #pragma unroll 4
    for (int g = gw; g < ngroups; g += nw) {
        const int f = g * 8 + fidx;
        const float* row = logits + (size_t)f * CC + sub * 8;
        const float4 v0 = *reinterpret_cast<const float4*>(row);
        const float4 v1 = *reinterpret_cast<const float4*>(row + 4);
        // local max over 8 cols
        float m = fmaxf(fmaxf(fmaxf(v0.x, v0.y), fmaxf(v0.z, v0.w)),
                        fmaxf(fmaxf(v1.x, v1.y), fmaxf(v1.z, v1.w)));
        // 8-lane max reduce via DPP rotations/mirrors (pure VALU)
        m = fmaxf(m, dppf<0x141>(m));   // ^7
        m = fmaxf(m, dppf<0x4E>(m));    // ^2
        m = fmaxf(m, dppf<0xB1>(m));    // ^1
        // local first index equal to global max
        const int c0 = sub * 8;
        int li = 64;
        if (v1.w == m) li = c0 + 7;
        if (v1.z == m) li = c0 + 6;
        if (v1.y == m) li = c0 + 5;
        if (v1.x == m) li = c0 + 4;
        if (v0.w == m) li = c0 + 3;
        if (v0.z == m) li = c0 + 2;
        if (v0.y == m) li = c0 + 1;
        if (v0.x == m) li = c0 + 0;
        // 8-lane min-index reduce
        li = min(li, dppi<0x141>(li));
        li = min(li, dppi<0x4E>(li));
        li = min(li, dppi<0xB1>(li));
        if (sub == 0) preds[f] = mask[f] ? -1 : li;
    }
}

// ---------------- K2: per-batch RLE + compaction scans + pad write ----------------
// One block (1024 threads) per batch. LDS: preds row + seg_start + partials.
__global__ __launch_bounds__(1024) void k_rle(const int* __restrict__ preds,
                                              int* __restrict__ g_start,
                                              int* __restrict__ g_count,
                                              int* __restrict__ g_newsz,
                                              float* __restrict__ out_pad) {
    __shared__ int s_pred[TT];
    __shared__ int s_start[TT];
    __shared__ int s_part[1024];
    const int b   = blockIdx.x;
    const int tid = threadIdx.x;
    const int NT  = 1024;
    const int CHUNK = TT / NT;     // 8
    const int t0 = tid * CHUNK;

    // load preds row (int4 vectorized)
    {
        const int4* src = reinterpret_cast<const int4*>(preds + (size_t)b * TT);
        int4* dst = reinterpret_cast<int4*>(s_pred);
        for (int i = tid; i < TT / 4; i += NT) dst[i] = src[i];
    }
    __syncthreads();

    // ---- scan 1: boundaries -> segment starts ----
    int local = 0;
    for (int t = t0; t < t0 + CHUNK; ++t) {
        int bnd = (t == 0) || (s_pred[t] != s_pred[t - 1]);
        local += bnd;
    }
    s_part[tid] = local;
    __syncthreads();
    for (int off = 1; off < NT; off <<= 1) {
        int v = (tid >= off) ? s_part[tid - off] : 0;
        __syncthreads();
        s_part[tid] += v;
        __syncthreads();
    }
    const int num_segs = s_part[NT - 1];
    int run = (tid > 0) ? s_part[tid - 1] : 0;
    for (int t = t0; t < t0 + CHUNK; ++t) {
        int bnd = (t == 0) || (s_pred[t] != s_pred[t - 1]);
        if (bnd) { run++; s_start[run - 1] = t; }
    }
    __syncthreads();

    // ---- scan 2: keep -> compacted positions; emit (start,count) ----
    int lk = 0;
    for (int s = t0; s < t0 + CHUNK; ++s) {
        if (s < num_segs && s_pred[s_start[s]] != -1) lk++;
    }
    __syncthreads();
    s_part[tid] = lk;
    __syncthreads();
    for (int off = 1; off < NT; off <<= 1) {
        int v = (tid >= off) ? s_part[tid - off] : 0;
        __syncthreads();
        s_part[tid] += v;
        __syncthreads();
    }
    int pos = (tid > 0) ? s_part[tid - 1] : 0;
    for (int s = t0; s < t0 + CHUNK; ++s) {
        if (s < num_segs) {
            const int st = s_start[s];
            if (s_pred[st] != -1) {
                const int end = (s + 1 < num_segs) ? s_start[s + 1] : TT;
                g_start[(size_t)b * TT + pos] = st;
                g_count[(size_t)b * TT + pos] = end - st;
                pos++;
            }
        }
    }
    const int nsz = s_part[NT - 1];
    if (tid == 0) g_newsz[b] = nsz;

    // ---- write out_pad row for this batch (coalesced float4, nontemporal) ----
    float* padrow = out_pad + (size_t)b * TT;
    for (int i = tid; i < TT / 4; i += NT) {
        const int p = i * 4;
        vfloat4 v = { p     >= nsz ? 1.f : 0.f,
                      p + 1 >= nsz ? 1.f : 0.f,
                      p + 2 >= nsz ? 1.f : 0.f,
                      p + 3 >= nsz ? 1.f : 0.f };
        __builtin_nontemporal_store(v, reinterpret_cast<vfloat4*>(padrow + p));
    }
}

// ---------------- K3: segment means -> compacted rows; zero tail ----------------
// 8 lanes per output row (2x float4 = 32B/lane), 8 rows per wave per iteration.
// Nontemporal stores: output is write-once; keep logits resident in L2/L3.
__global__ __launch_bounds__(256) void k_out(const float* __restrict__ logits,
                                             const int* __restrict__ g_start,
                                             const int* __restrict__ g_count,
                                             const int* __restrict__ g_newsz,
                                             float* __restrict__ out_logits) {
    __shared__ int s_nsz[BB];
    if (threadIdx.x < BB) s_nsz[threadIdx.x] = g_newsz[threadIdx.x];
    __syncthreads();

    const int lane = threadIdx.x & 63;
    const int wave = threadIdx.x >> 6;
    const int sub  = lane & 7;    // column octet within row
    const int ridx = lane >> 3;   // row within group of 8
    const int wavesPerBlock = blockDim.x >> 6;
    const int gw = blockIdx.x * wavesPerBlock + wave;
    const int nw = gridDim.x * wavesPerBlock;
    const int ngroups = (BB * TT) >> 3;   // 8 rows per wave-iteration

    for (int g = gw; g < ngroups; g += nw) {
        const int row = g * 8 + ridx;
        const int b = row >> 13;          // / TT
        const int p = row & (TT - 1);     // % TT
        const int nsz = s_nsz[b];
        vfloat4 o0 = {0.f, 0.f, 0.f, 0.f};
        vfloat4 o1 = {0.f, 0.f, 0.f, 0.f};
        if (p < nsz) {
            const int st  = g_start[row];
            const int cnt = g_count[row];
            const float* src = logits + ((size_t)b * TT + st) * CC + sub * 8;
            vfloat4 a0 = *reinterpret_cast<const vfloat4*>(src);
            vfloat4 a1 = *reinterpret_cast<const vfloat4*>(src + 4);
            for (int f = 1; f < cnt; ++f) {
                a0 += *reinterpret_cast<const vfloat4*>(src + (size_t)f * CC);
                a1 += *reinterpret_cast<const vfloat4*>(src + (size_t)f * CC + 4);
            }
            const float inv = 1.0f / (float)cnt;
            o0 = a0 * inv;
            o1 = a1 * inv;
        }
        float* dst = out_logits + (size_t)row * CC + sub * 8;
        __builtin_nontemporal_store(o0, reinterpret_cast<vfloat4*>(dst));
        __builtin_nontemporal_store(o1, reinterpret_cast<vfloat4*>(dst + 4));
    }
}

extern "C" void kernel_launch(void* const* d_in, const int* in_sizes, int n_in,
                              void* d_out, int out_size, void* d_ws, size_t ws_size,
                              hipStream_t stream) {
    const float* logits = (const float*)d_in[0];
    const int*   mask   = (const int*)d_in[1];   // jax bool -> int32 (harness rule)

    int* preds   = (int*)d_ws;                   // B*T
    int* g_start = preds   + (size_t)BB * TT;    // B*T
    int* g_count = g_start + (size_t)BB * TT;    // B*T
    int* g_newsz = g_count + (size_t)BB * TT;    // B

    float* out_logits = (float*)d_out;
    float* out_pad    = out_logits + (size_t)BB * TT * CC;

    hipLaunchKernelGGL(k_argmax, dim3(2048), dim3(256), 0, stream,
                       logits, mask, preds);
    hipLaunchKernelGGL(k_rle, dim3(BB), dim3(1024), 0, stream,
                       preds, g_start, g_count, g_newsz, out_pad);
    hipLaunchKernelGGL(k_out, dim3(2048), dim3(256), 0, stream,
                       logits, g_start, g_count, g_newsz, out_logits);
}

// Round 5
// 75.221 us; speedup vs baseline: 1.2184x; 1.2184x over previous
//
#include <hip/hip_runtime.h>

#define BB 64
#define TT 8192
#define CC 64

typedef float vfloat4 __attribute__((ext_vector_type(4)));

// DPP cross-lane helpers (VALU-only, no LDS). CTRL: 0x141 = row_half_mirror
// (lane^7 within each 8-group), 0x4E = quad_perm [2,3,0,1] (lane^2),
// 0xB1 = quad_perm [1,0,3,2] (lane^1). All stay within an 8-lane group.
template<int CTRL>
__device__ __forceinline__ float dppf(float x) {
    return __int_as_float(__builtin_amdgcn_update_dpp(
        0, __float_as_int(x), CTRL, 0xF, 0xF, true));
}
template<int CTRL>
__device__ __forceinline__ int dppi(int x) {
    return __builtin_amdgcn_update_dpp(0, x, CTRL, 0xF, 0xF, true);
}

// ---------------- K1: masked argmax over C=64 -> preds[B*T] ----------------
// 8 lanes per frame, 8 cols/lane (2x float4), DPP-only reduction.
// Tie-break: first (lowest) index, exact vs np.argmax.
__global__ __launch_bounds__(256) void k_argmax(const float* __restrict__ logits,
                                                const int* __restrict__ mask,
                                                int* __restrict__ preds) {
    const int lane = threadIdx.x & 63;
    const int wave = threadIdx.x >> 6;
    const int sub  = lane & 7;    // column octet within frame
    const int fidx = lane >> 3;   // frame within group of 8
    const int wavesPerBlock = blockDim.x >> 6;
    const int gw = blockIdx.x * wavesPerBlock + wave;
    const int nw = gridDim.x * wavesPerBlock;
    const int ngroups = (BB * TT) >> 3;   // 8 frames per wave-iteration

    #pragma unroll 2
    for (int g = gw; g < ngroups; g += nw) {
        const int f = g * 8 + fidx;
        const float* row = logits + (size_t)f * CC + sub * 8;
        const float4 v0 = *reinterpret_cast<const float4*>(row);
        const float4 v1 = *reinterpret_cast<const float4*>(row + 4);
        // local max over 8 cols
        float m = fmaxf(fmaxf(fmaxf(v0.x, v0.y), fmaxf(v0.z, v0.w)),
                        fmaxf(fmaxf(v1.x, v1.y), fmaxf(v1.z, v1.w)));
        // 8-lane max reduce via DPP rotations/mirrors (pure VALU)
        m = fmaxf(m, dppf<0x141>(m));   // ^7
        m = fmaxf(m, dppf<0x4E>(m));    // ^2
        m = fmaxf(m, dppf<0xB1>(m));    // ^1
        // local first index equal to global max
        const int c0 = sub * 8;
        int li = 64;
        if (v1.w == m) li = c0 + 7;
        if (v1.z == m) li = c0 + 6;
        if (v1.y == m) li = c0 + 5;
        if (v1.x == m) li = c0 + 4;
        if (v0.w == m) li = c0 + 3;
        if (v0.z == m) li = c0 + 2;
        if (v0.y == m) li = c0 + 1;
        if (v0.x == m) li = c0 + 0;
        // 8-lane min-index reduce
        li = min(li, dppi<0x141>(li));
        li = min(li, dppi<0x4E>(li));
        li = min(li, dppi<0xB1>(li));
        if (sub == 0) preds[f] = mask[f] ? -1 : li;
    }
}

// ---------------- K2: per-batch RLE + compaction scans + pad write ----------------
// One block (1024 threads) per batch. Emits packed (start | count<<14) per
// compacted segment (start<8192: 13 bits; count<=8192: 14+ bits fits).
__global__ __launch_bounds__(1024) void k_rle(const int* __restrict__ preds,
                                              unsigned int* __restrict__ g_sc,
                                              int* __restrict__ g_newsz,
                                              float* __restrict__ out_pad) {
    __shared__ int s_pred[TT];
    __shared__ int s_start[TT];
    __shared__ int s_part[1024];
    const int b   = blockIdx.x;
    const int tid = threadIdx.x;
    const int NT  = 1024;
    const int CHUNK = TT / NT;     // 8
    const int t0 = tid * CHUNK;

    // load preds row (int4 vectorized)
    {
        const int4* src = reinterpret_cast<const int4*>(preds + (size_t)b * TT);
        int4* dst = reinterpret_cast<int4*>(s_pred);
        for (int i = tid; i < TT / 4; i += NT) dst[i] = src[i];
    }
    __syncthreads();

    // ---- scan 1: boundaries -> segment starts ----
    int local = 0;
    for (int t = t0; t < t0 + CHUNK; ++t) {
        int bnd = (t == 0) || (s_pred[t] != s_pred[t - 1]);
        local += bnd;
    }
    s_part[tid] = local;
    __syncthreads();
    for (int off = 1; off < NT; off <<= 1) {
        int v = (tid >= off) ? s_part[tid - off] : 0;
        __syncthreads();
        s_part[tid] += v;
        __syncthreads();
    }
    const int num_segs = s_part[NT - 1];
    int run = (tid > 0) ? s_part[tid - 1] : 0;
    for (int t = t0; t < t0 + CHUNK; ++t) {
        int bnd = (t == 0) || (s_pred[t] != s_pred[t - 1]);
        if (bnd) { run++; s_start[run - 1] = t; }
    }
    __syncthreads();

    // ---- scan 2: keep -> compacted positions; emit packed (start,count) ----
    int lk = 0;
    for (int s = t0; s < t0 + CHUNK; ++s) {
        if (s < num_segs && s_pred[s_start[s]] != -1) lk++;
    }
    __syncthreads();
    s_part[tid] = lk;
    __syncthreads();
    for (int off = 1; off < NT; off <<= 1) {
        int v = (tid >= off) ? s_part[tid - off] : 0;
        __syncthreads();
        s_part[tid] += v;
        __syncthreads();
    }
    int pos = (tid > 0) ? s_part[tid - 1] : 0;
    for (int s = t0; s < t0 + CHUNK; ++s) {
        if (s < num_segs) {
            const int st = s_start[s];
            if (s_pred[st] != -1) {
                const int end = (s + 1 < num_segs) ? s_start[s + 1] : TT;
                g_sc[(size_t)b * TT + pos] =
                    (unsigned int)st | ((unsigned int)(end - st) << 14);
                pos++;
            }
        }
    }
    const int nsz = s_part[NT - 1];
    if (tid == 0) g_newsz[b] = nsz;

    // ---- write out_pad row for this batch (coalesced float4) ----
    float* padrow = out_pad + (size_t)b * TT;
    for (int i = tid; i < TT / 4; i += NT) {
        const int p = i * 4;
        vfloat4 v = { p     >= nsz ? 1.f : 0.f,
                      p + 1 >= nsz ? 1.f : 0.f,
                      p + 2 >= nsz ? 1.f : 0.f,
                      p + 3 >= nsz ? 1.f : 0.f };
        *reinterpret_cast<vfloat4*>(padrow + p) = v;
    }
}

// ---------------- K3: segment means -> compacted rows; zero tail ----------------
// 16 lanes per output row (float4 = 16B/lane dense), 4 rows per wave per iter.
__global__ __launch_bounds__(256) void k_out(const float* __restrict__ logits,
                                             const unsigned int* __restrict__ g_sc,
                                             const int* __restrict__ g_newsz,
                                             float* __restrict__ out_logits) {
    __shared__ int s_nsz[BB];
    if (threadIdx.x < BB) s_nsz[threadIdx.x] = g_newsz[threadIdx.x];
    __syncthreads();

    const int lane = threadIdx.x & 63;
    const int wave = threadIdx.x >> 6;
    const int sub  = lane & 15;   // column quad within row
    const int ridx = lane >> 4;   // row within group of 4
    const int wavesPerBlock = blockDim.x >> 6;
    const int gw = blockIdx.x * wavesPerBlock + wave;
    const int nw = gridDim.x * wavesPerBlock;
    const int ngroups = (BB * TT) >> 2;   // 4 rows per wave-iteration

    for (int g = gw; g < ngroups; g += nw) {
        const int row = g * 4 + ridx;
        const int b = row >> 13;          // / TT
        const int p = row & (TT - 1);     // % TT
        const int nsz = s_nsz[b];
        vfloat4 val = {0.f, 0.f, 0.f, 0.f};
        if (p < nsz) {
            const unsigned int sc = g_sc[row];
            const int st  = (int)(sc & 16383u);
            const int cnt = (int)(sc >> 14);
            const float* src = logits + ((size_t)b * TT + st) * CC + sub * 4;
            vfloat4 acc = *reinterpret_cast<const vfloat4*>(src);
            for (int f = 1; f < cnt; ++f) {
                acc += *reinterpret_cast<const vfloat4*>(src + (size_t)f * CC);
            }
            val = acc * (1.0f / (float)cnt);
        }
        *reinterpret_cast<vfloat4*>(out_logits + (size_t)row * CC + sub * 4) = val;
    }
}

extern "C" void kernel_launch(void* const* d_in, const int* in_sizes, int n_in,
                              void* d_out, int out_size, void* d_ws, size_t ws_size,
                              hipStream_t stream) {
    const float* logits = (const float*)d_in[0];
    const int*   mask   = (const int*)d_in[1];   // jax bool -> int32 (harness rule)

    int*          preds   = (int*)d_ws;                       // B*T
    unsigned int* g_sc    = (unsigned int*)(preds + (size_t)BB * TT);  // B*T
    int*          g_newsz = (int*)(g_sc + (size_t)BB * TT);   // B

    float* out_logits = (float*)d_out;
    float* out_pad    = out_logits + (size_t)BB * TT * CC;

    hipLaunchKernelGGL(k_argmax, dim3(2048), dim3(256), 0, stream,
                       logits, mask, preds);
    hipLaunchKernelGGL(k_rle, dim3(BB), dim3(1024), 0, stream,
                       preds, g_sc, g_newsz, out_pad);
    hipLaunchKernelGGL(k_out, dim3(2048), dim3(256), 0, stream,
                       logits, g_sc, g_newsz, out_logits);
}

// Round 6
// 68.458 us; speedup vs baseline: 1.3387x; 1.0988x over previous
//
#include <hip/hip_runtime.h>

#define BB 64
#define TT 8192
#define CC 64

typedef float vfloat4 __attribute__((ext_vector_type(4)));

// DPP cross-lane helpers (VALU-only, no LDS). CTRL: 0x141 = row_half_mirror
// (lane^7 within each 8-group), 0x4E = quad_perm [2,3,0,1] (lane^2),
// 0xB1 = quad_perm [1,0,3,2] (lane^1). All stay within an 8-lane group.
template<int CTRL>
__device__ __forceinline__ float dppf(float x) {
    return __int_as_float(__builtin_amdgcn_update_dpp(
        0, __float_as_int(x), CTRL, 0xF, 0xF, true));
}
template<int CTRL>
__device__ __forceinline__ int dppi(int x) {
    return __builtin_amdgcn_update_dpp(0, x, CTRL, 0xF, 0xF, true);
}

// ---------------- K1: masked argmax over C=64 -> preds[B*T] ----------------
// 8 lanes per frame, 8 cols/lane (2x float4), DPP-only reduction.
// Masked frames skip the 256B logits read entirely (wave-coherent tails).
__global__ __launch_bounds__(256) void k_argmax(const float* __restrict__ logits,
                                                const int* __restrict__ mask,
                                                int* __restrict__ preds) {
    const int lane = threadIdx.x & 63;
    const int wave = threadIdx.x >> 6;
    const int sub  = lane & 7;    // column octet within frame
    const int fidx = lane >> 3;   // frame within group of 8
    const int wavesPerBlock = blockDim.x >> 6;
    const int gw = blockIdx.x * wavesPerBlock + wave;
    const int nw = gridDim.x * wavesPerBlock;
    const int ngroups = (BB * TT) >> 3;   // 8 frames per wave-iteration

    #pragma unroll 2
    for (int g = gw; g < ngroups; g += nw) {
        const int f = g * 8 + fidx;
        const int mk = mask[f];
        int li = -1;
        if (!mk) {
            const float* row = logits + (size_t)f * CC + sub * 8;
            const float4 v0 = *reinterpret_cast<const float4*>(row);
            const float4 v1 = *reinterpret_cast<const float4*>(row + 4);
            // local max over 8 cols
            float m = fmaxf(fmaxf(fmaxf(v0.x, v0.y), fmaxf(v0.z, v0.w)),
                            fmaxf(fmaxf(v1.x, v1.y), fmaxf(v1.z, v1.w)));
            // 8-lane max reduce via DPP (pure VALU; all 8 lanes of a frame
            // share the mask, so active groups are fully active)
            m = fmaxf(m, dppf<0x141>(m));   // ^7
            m = fmaxf(m, dppf<0x4E>(m));    // ^2
            m = fmaxf(m, dppf<0xB1>(m));    // ^1
            // local first index equal to global max
            const int c0 = sub * 8;
            int t = 64;
            if (v1.w == m) t = c0 + 7;
            if (v1.z == m) t = c0 + 6;
            if (v1.y == m) t = c0 + 5;
            if (v1.x == m) t = c0 + 4;
            if (v0.w == m) t = c0 + 3;
            if (v0.z == m) t = c0 + 2;
            if (v0.y == m) t = c0 + 1;
            if (v0.x == m) t = c0 + 0;
            // 8-lane min-index reduce
            t = min(t, dppi<0x141>(t));
            t = min(t, dppi<0x4E>(t));
            t = min(t, dppi<0xB1>(t));
            li = t;
        }
        if (sub == 0) preds[f] = li;
    }
}

// ---------------- block-wide exclusive scan (1024 thr = 16 waves) ----------------
// Wave-level shfl_up scan + 16-entry wave-sum combine. ~3 barriers total.
__device__ __forceinline__ void block_scan(int x, int tid, int* s_wsum,
                                           int& excl, int& total) {
    const int lane = tid & 63;
    const int wv   = tid >> 6;
    int v = x;
    #pragma unroll
    for (int d = 1; d < 64; d <<= 1) {
        int t = __shfl_up(v, d);
        if (lane >= d) v += t;
    }
    __syncthreads();                 // s_wsum safe to overwrite
    if (lane == 63) s_wsum[wv] = v;
    __syncthreads();
    int wpre = 0, tot = 0;
    #pragma unroll
    for (int w = 0; w < 16; ++w) {
        const int s = s_wsum[w];
        tot += s;
        if (w < wv) wpre += s;
    }
    excl = wpre + v - x;
    total = tot;
}

// ---------------- K2: per-batch RLE + compaction scans + pad write ----------------
// One block (1024 threads) per batch. Emits packed (start | count<<14).
__global__ __launch_bounds__(1024) void k_rle(const int* __restrict__ preds,
                                              unsigned int* __restrict__ g_sc,
                                              int* __restrict__ g_newsz,
                                              float* __restrict__ out_pad) {
    __shared__ int s_pred[TT];
    __shared__ int s_start[TT];
    __shared__ int s_wsum[16];
    const int b   = blockIdx.x;
    const int tid = threadIdx.x;
    const int NT  = 1024;
    const int CHUNK = TT / NT;     // 8
    const int t0 = tid * CHUNK;

    // load preds row (int4 vectorized)
    {
        const int4* src = reinterpret_cast<const int4*>(preds + (size_t)b * TT);
        int4* dst = reinterpret_cast<int4*>(s_pred);
        for (int i = tid; i < TT / 4; i += NT) dst[i] = src[i];
    }
    __syncthreads();

    // ---- scan 1: boundaries -> segment starts ----
    int local = 0;
    for (int t = t0; t < t0 + CHUNK; ++t) {
        local += (t == 0) || (s_pred[t] != s_pred[t - 1]);
    }
    int run, num_segs;
    block_scan(local, tid, s_wsum, run, num_segs);
    for (int t = t0; t < t0 + CHUNK; ++t) {
        int bnd = (t == 0) || (s_pred[t] != s_pred[t - 1]);
        if (bnd) { run++; s_start[run - 1] = t; }
    }
    __syncthreads();

    // ---- scan 2: keep -> compacted positions; emit packed (start,count) ----
    int lk = 0;
    for (int s = t0; s < t0 + CHUNK; ++s) {
        if (s < num_segs && s_pred[s_start[s]] != -1) lk++;
    }
    int pos, nsz;
    block_scan(lk, tid, s_wsum, pos, nsz);
    for (int s = t0; s < t0 + CHUNK; ++s) {
        if (s < num_segs) {
            const int st = s_start[s];
            if (s_pred[st] != -1) {
                const int end = (s + 1 < num_segs) ? s_start[s + 1] : TT;
                g_sc[(size_t)b * TT + pos] =
                    (unsigned int)st | ((unsigned int)(end - st) << 14);
                pos++;
            }
        }
    }
    if (tid == 0) g_newsz[b] = nsz;

    // ---- write out_pad row for this batch (coalesced float4) ----
    float* padrow = out_pad + (size_t)b * TT;
    for (int i = tid; i < TT / 4; i += NT) {
        const int p = i * 4;
        vfloat4 v = { p     >= nsz ? 1.f : 0.f,
                      p + 1 >= nsz ? 1.f : 0.f,
                      p + 2 >= nsz ? 1.f : 0.f,
                      p + 3 >= nsz ? 1.f : 0.f };
        *reinterpret_cast<vfloat4*>(padrow + p) = v;
    }
}

// ---------------- K3: segment means -> compacted rows; zero tail ----------------
// 16 lanes per output row (float4 = 16B/lane dense), 4 rows per wave per iter.
__global__ __launch_bounds__(256) void k_out(const float* __restrict__ logits,
                                             const unsigned int* __restrict__ g_sc,
                                             const int* __restrict__ g_newsz,
                                             float* __restrict__ out_logits) {
    __shared__ int s_nsz[BB];
    if (threadIdx.x < BB) s_nsz[threadIdx.x] = g_newsz[threadIdx.x];
    __syncthreads();

    const int lane = threadIdx.x & 63;
    const int wave = threadIdx.x >> 6;
    const int sub  = lane & 15;   // column quad within row
    const int ridx = lane >> 4;   // row within group of 4
    const int wavesPerBlock = blockDim.x >> 6;
    const int gw = blockIdx.x * wavesPerBlock + wave;
    const int nw = gridDim.x * wavesPerBlock;
    const int ngroups = (BB * TT) >> 2;   // 4 rows per wave-iteration

    for (int g = gw; g < ngroups; g += nw) {
        const int row = g * 4 + ridx;
        const int b = row >> 13;          // / TT
        const int p = row & (TT - 1);     // % TT
        const int nsz = s_nsz[b];
        vfloat4 val = {0.f, 0.f, 0.f, 0.f};
        if (p < nsz) {
            const unsigned int sc = g_sc[row];
            const int st  = (int)(sc & 16383u);
            const int cnt = (int)(sc >> 14);
            const float* src = logits + ((size_t)b * TT + st) * CC + sub * 4;
            vfloat4 acc = *reinterpret_cast<const vfloat4*>(src);
            for (int f = 1; f < cnt; ++f) {
                acc += *reinterpret_cast<const vfloat4*>(src + (size_t)f * CC);
            }
            val = acc * (1.0f / (float)cnt);
        }
        *reinterpret_cast<vfloat4*>(out_logits + (size_t)row * CC + sub * 4) = val;
    }
}

extern "C" void kernel_launch(void* const* d_in, const int* in_sizes, int n_in,
                              void* d_out, int out_size, void* d_ws, size_t ws_size,
                              hipStream_t stream) {
    const float* logits = (const float*)d_in[0];
    const int*   mask   = (const int*)d_in[1];   // jax bool -> int32 (harness rule)

    int*          preds   = (int*)d_ws;                       // B*T
    unsigned int* g_sc    = (unsigned int*)(preds + (size_t)BB * TT);  // B*T
    int*          g_newsz = (int*)(g_sc + (size_t)BB * TT);   // B

    float* out_logits = (float*)d_out;
    float* out_pad    = out_logits + (size_t)BB * TT * CC;

    hipLaunchKernelGGL(k_argmax, dim3(2048), dim3(256), 0, stream,
                       logits, mask, preds);
    hipLaunchKernelGGL(k_rle, dim3(BB), dim3(1024), 0, stream,
                       preds, g_sc, g_newsz, out_pad);
    hipLaunchKernelGGL(k_out, dim3(2048), dim3(256), 0, stream,
                       logits, g_sc, g_newsz, out_logits);
}